// Round 5
// baseline (330.190 us; speedup 1.0000x reference)
//
#include <hip/hip_runtime.h>
#include <hip/hip_bf16.h>

// MemoryEfficientMultiheadAttention: chunked (block-diagonal) MHA.
// S=4096, B=4, D=1024, H=16, dk=64, CHUNK=256.
// cvt(weights, qkv->bf16) -> fused QKV GEMM (LDS-staged head-major epilogue)
//   -> flash attn (swapped QK^T, lane-local softmax, P-in-reg PV) -> out proj.

namespace {

constexpr int kSeq = 4096, kB = 4, kDm = 1024, kNh = 16, kDk = 64, kChk = 256;
constexpr int kMr = kSeq * kB;       // 16384 GEMM rows
constexpr float kLog2e = 1.44269504088896340736f;

typedef __attribute__((ext_vector_type(8))) short bf16x8;
typedef __attribute__((ext_vector_type(4))) short bf16x4;
typedef __attribute__((ext_vector_type(4))) float f32x4;
typedef __attribute__((ext_vector_type(8))) unsigned short u16x8;
typedef __attribute__((ext_vector_type(4))) unsigned short u16x4;

__device__ __forceinline__ unsigned short f2bf(float x) {
  union { float f; unsigned u; } v; v.f = x;
  unsigned r = v.u + 0x7fffu + ((v.u >> 16) & 1u);   // RNE
  return (unsigned short)(r >> 16);
}
// XOR swizzle for 128B-row-stride LDS tiles: xor byte bits 4-6 with row&7.
__device__ __forceinline__ int swz(int bo) { return bo ^ ((bo >> 3) & 0x70); }

__device__ __forceinline__ f32x4 mfma16x16(bf16x4 a, bf16x4 b, f32x4 c) {
#if __has_builtin(__builtin_amdgcn_mfma_f32_16x16x16bf16_1k)
  return __builtin_amdgcn_mfma_f32_16x16x16bf16_1k(a, b, c, 0, 0, 0);
#else
  asm volatile("v_mfma_f32_16x16x16_bf16 %0, %1, %2, %0\n\ts_nop 4"
               : "+v"(c) : "v"(a), "v"(b));
  return c;
#endif
}

// All four 1024x1024 weights -> bf16, dst contiguous (Wq|Wk|Wv|Wo).
__global__ __launch_bounds__(256) void cvt4(const float* __restrict__ s0,
                                            const float* __restrict__ s1,
                                            const float* __restrict__ s2,
                                            const float* __restrict__ s3,
                                            unsigned short* __restrict__ dst) {
  int i = blockIdx.x * 256 + threadIdx.x;          // 0 .. 4*2^18-1
  int t = i >> 18;
  int j = i & 0x3ffff;
  const float* s = (t == 0) ? s0 : (t == 1) ? s1 : (t == 2) ? s2 : s3;
  f32x4 v = *(const f32x4*)(s + (size_t)j * 4);
  u16x4 o;
  o[0] = f2bf(v[0]); o[1] = f2bf(v[1]); o[2] = f2bf(v[2]); o[3] = f2bf(v[3]);
  *(u16x4*)(dst + (size_t)i * 4) = o;
}

// query|key|value fp32 -> bf16, three contiguous 16M-elem tensors.
__global__ __launch_bounds__(256) void cvt3(const float* __restrict__ s0,
                                            const float* __restrict__ s1,
                                            const float* __restrict__ s2,
                                            unsigned short* __restrict__ dst) {
  size_t i = (size_t)blockIdx.x * 256 + threadIdx.x;   // 3 * 2^22 chunks
  int t = (int)(i >> 22);
  size_t j = i & 0x3fffff;
  const float* s = (t == 0) ? s0 : (t == 1) ? s1 : s2;
  f32x4 v = *(const f32x4*)(s + j * 4);
  u16x4 o;
  o[0] = f2bf(v[0]); o[1] = f2bf(v[1]); o[2] = f2bf(v[2]); o[3] = f2bf(v[3]);
  *(u16x4*)(dst + i * 4) = o;
}

// Fused QKV projection: C_mat = A_mat @ W_mat^T + b_mat, mat in {q,k,v}.
// Wcat = rows 0..3071 of (Wq|Wk|Wv); out bf16 head-major (B,H,S,dk), scaled.
// 128x128 tile, BK=32, 4 waves, 2-phase dbuf, XCD-swizzled grid (3072 blocks).
// Epilogue stages C through the (now dead) 32KB staging LDS for coalesced
// head-major stores: thread -> one contiguous 128B output row.
__global__ __launch_bounds__(256) void gemm_qkv(const unsigned short* __restrict__ qbf,
                                                const unsigned short* __restrict__ kbf,
                                                const unsigned short* __restrict__ vbf,
                                                const unsigned short* __restrict__ Wcat,
                                                const float* __restrict__ bq,
                                                const float* __restrict__ bk,
                                                const float* __restrict__ bv,
                                                unsigned short* __restrict__ dst,
                                                float sQ) {
  constexpr int K = kDm;
  __shared__ unsigned short sh[16384];             // As(2x8KB) | Bs(2x8KB); epilogue: C
  const int tid = (int)threadIdx.x;
  const int l = tid & 63;
  const int wbase = tid & ~63;
  const int bid = (int)blockIdx.x;
  const int lin = (bid & 7) * 384 + (bid >> 3);    // bijective: 3072 % 8 == 0
  const int rbi = lin / 24, cbi = lin % 24;        // cb fastest: A-tile L2 reuse
  const int rb = rbi * 128;
  const int mat = cbi >> 3, ccol = (cbi & 7) * 128;
  const unsigned short* A = (mat == 0) ? qbf : (mat == 1) ? kbf : vbf;
  const float* bp = (mat == 0) ? bq : (mat == 1) ? bk : bv;
  const float scale = (mat == 0) ? sQ : 1.0f;
  unsigned short* out = dst + (size_t)mat * kMr * kDm;
  const int wr = ((tid >> 7) & 1) * 64;
  const int wc = ((tid >> 6) & 1) * 64;
  const int l15 = l & 15, l4 = l >> 4;

  f32x4 acc[4][4] = {};

  auto stage = [&](int buf, int k0) {
    unsigned short* AsB = sh + buf * 4096;
    unsigned short* BsB = sh + 8192 + buf * 4096;
#pragma unroll
    for (int i = 0; i < 2; ++i) {
      int ch = i * 256 + tid;
      int rr = ch >> 2, cc = ch & 3;
      const unsigned short* g = A + (size_t)(rb + rr) * K + (k0 + cc * 8);
      __builtin_amdgcn_global_load_lds(
          (const __attribute__((address_space(1))) unsigned int*)g,
          (__attribute__((address_space(3))) unsigned int*)&AsB[(i * 256 + wbase) * 8],
          16, 0, 0);
    }
#pragma unroll
    for (int i = 0; i < 2; ++i) {
      int ch = i * 256 + tid;
      int rr = ch >> 2, cc = ch & 3;
      const unsigned short* g = Wcat + (size_t)(cbi * 128 + rr) * K + (k0 + cc * 8);
      __builtin_amdgcn_global_load_lds(
          (const __attribute__((address_space(1))) unsigned int*)g,
          (__attribute__((address_space(3))) unsigned int*)&BsB[(i * 256 + wbase) * 8],
          16, 0, 0);
    }
  };

  stage(0, 0);
  __syncthreads();
  int cur = 0;
  constexpr int nkt = K >> 5;
  for (int kt = 0; kt < nkt; ++kt) {
    if (kt + 1 < nkt) stage(cur ^ 1, (kt + 1) << 5);
    const unsigned short* AsC = sh + cur * 4096;
    const unsigned short* BsC = sh + 8192 + cur * 4096;
    bf16x8 af[4], bfr[4];
#pragma unroll
    for (int m = 0; m < 4; ++m)
      af[m] = *(const bf16x8*)&AsC[(wr + m * 16 + l15) * 32 + l4 * 8];
#pragma unroll
    for (int n = 0; n < 4; ++n)
      bfr[n] = *(const bf16x8*)&BsC[(wc + n * 16 + l15) * 32 + l4 * 8];
#pragma unroll
    for (int m = 0; m < 4; ++m)
#pragma unroll
      for (int n = 0; n < 4; ++n)
        acc[m][n] = __builtin_amdgcn_mfma_f32_16x16x32_bf16(af[m], bfr[n], acc[m][n], 0, 0, 0);
    __syncthreads();
    cur ^= 1;
  }

  // ---- LDS-staged head-major epilogue ----
  // C-tile rows t = rb + t_local; b2 = t_local&3, s_local = t_local>>2.
  // LDS layout: or = (b2*2 + hh)*32 + s_local (hh = tile-local head half),
  // 64 bf16 per or-row (128B), byte addr swizzled ^((or&7)<<4).
#pragma unroll
  for (int n = 0; n < 4; ++n) {
    int col = wc + n * 16 + l15;                 // tile-local col (< 128)
    float bvv = bp[ccol + col];
    int hh = col >> 6, c64 = col & 63;
#pragma unroll
    for (int m = 0; m < 4; ++m) {
      int sl0 = (wr >> 2) + m * 4 + l4;          // s_local (j-independent)
#pragma unroll
      for (int j = 0; j < 4; ++j) {
        int or_ = (j * 2 + hh) * 32 + sl0;
        int bo = or_ * 128 + c64 * 2;
        *(unsigned short*)((char*)sh + (bo ^ ((or_ & 7) << 4))) =
            f2bf((acc[m][n][j] + bvv) * scale);
      }
    }
  }
  __syncthreads();
  {
    int s_local = tid & 31, grp = tid >> 5;      // grp = b2*2 + hh
    int b2 = grp >> 1, hh = grp & 1;
    int h = (ccol >> 6) + hh;
    unsigned short* po =
        out + ((size_t)(b2 * kNh + h) * kSeq + (rb >> 2) + s_local) * kDk;
    const int or_ = tid;
#pragma unroll
    for (int i = 0; i < 8; ++i) {
      int bo = or_ * 128 + i * 16;
      u16x8 vv = *(const u16x8*)((const char*)sh + (bo ^ ((or_ & 7) << 4)));
      *(u16x8*)(po + i * 8) = vv;
    }
  }
}

// C = A @ Bw^T + bias (single matrix). Used for out-proj and the fallback path.
// ALAY: 1 = A fp32 row-major (reg-staged+cvt); 2 = A bf16 head-major.
// OHM:  1 = out bf16 head-major, scaled;  0 = out fp32 row-major.
template <int ALAY, int OHM>
__global__ __launch_bounds__(256) void gemm_bt(const void* __restrict__ Ap,
                                               const unsigned short* __restrict__ Bw,
                                               const float* __restrict__ bias,
                                               void* __restrict__ Cp, float scale) {
  constexpr int K = kDm, N = kDm;
  __shared__ unsigned short As[2][128 * 32];
  __shared__ unsigned short Bs[2][128 * 32];
  const int tid = (int)threadIdx.x;
  const int l = tid & 63;
  const int wbase = tid & ~63;
  const int bid = (int)blockIdx.x;
  const int lin = (bid & 7) * 128 + (bid >> 3);
  const int rb = (lin >> 3) * 128, cb = (lin & 7) * 128;
  const int wr = ((tid >> 7) & 1) * 64;
  const int wc = ((tid >> 6) & 1) * 64;
  const int l15 = l & 15, l4 = l >> 4;

  f32x4 acc[4][4] = {};

  auto stage = [&](int buf, int k0) {
    if constexpr (ALAY == 1) {
      const float* A = (const float*)Ap;
#pragma unroll
      for (int i = 0; i < 4; ++i) {
        int ci = tid + 256 * i;
        int rr = ci >> 3, c4 = ci & 7;
        f32x4 v = *(const f32x4*)(A + (size_t)(rb + rr) * K + (k0 + c4 * 4));
        u16x4 o;
        o[0] = f2bf(v[0]); o[1] = f2bf(v[1]); o[2] = f2bf(v[2]); o[3] = f2bf(v[3]);
        *(u16x4*)&As[buf][rr * 32 + c4 * 4] = o;
      }
    } else {
      const unsigned short* A = (const unsigned short*)Ap;
      int h = k0 >> 6, d0 = k0 & 63;
#pragma unroll
      for (int i = 0; i < 2; ++i) {
        int ch = i * 256 + tid;
        int rr = ch >> 2, cc = ch & 3;
        int t = rb + rr; int s = t >> 2, b2 = t & 3;
        const unsigned short* g =
            A + ((size_t)(b2 * kNh + h) * kSeq + s) * kDk + d0 + cc * 8;
        __builtin_amdgcn_global_load_lds(
            (const __attribute__((address_space(1))) unsigned int*)g,
            (__attribute__((address_space(3))) unsigned int*)&As[buf][(i * 256 + wbase) * 8],
            16, 0, 0);
      }
    }
#pragma unroll
    for (int i = 0; i < 2; ++i) {
      int ch = i * 256 + tid;
      int rr = ch >> 2, cc = ch & 3;
      const unsigned short* g = Bw + (size_t)(cb + rr) * K + (k0 + cc * 8);
      __builtin_amdgcn_global_load_lds(
          (const __attribute__((address_space(1))) unsigned int*)g,
          (__attribute__((address_space(3))) unsigned int*)&Bs[buf][(i * 256 + wbase) * 8],
          16, 0, 0);
    }
  };

  stage(0, 0);
  __syncthreads();
  int cur = 0;
  constexpr int nkt = K >> 5;
  for (int kt = 0; kt < nkt; ++kt) {
    if (kt + 1 < nkt) stage(cur ^ 1, (kt + 1) << 5);
    bf16x8 af[4], bfr[4];
#pragma unroll
    for (int m = 0; m < 4; ++m)
      af[m] = *(const bf16x8*)&As[cur][(wr + m * 16 + l15) * 32 + l4 * 8];
#pragma unroll
    for (int n = 0; n < 4; ++n)
      bfr[n] = *(const bf16x8*)&Bs[cur][(wc + n * 16 + l15) * 32 + l4 * 8];
#pragma unroll
    for (int m = 0; m < 4; ++m)
#pragma unroll
      for (int n = 0; n < 4; ++n)
        acc[m][n] = __builtin_amdgcn_mfma_f32_16x16x32_bf16(af[m], bfr[n], acc[m][n], 0, 0, 0);
    __syncthreads();
    cur ^= 1;
  }

#pragma unroll
  for (int n = 0; n < 4; ++n) {
    int col = cb + wc + n * 16 + l15;
    float bvv = bias[col];
    int h = col >> 6, dd = col & 63;
#pragma unroll
    for (int m = 0; m < 4; ++m) {
      int row0 = rb + wr + m * 16 + l4 * 4;
#pragma unroll
      for (int j = 0; j < 4; ++j) {
        float v = acc[m][n][j] + bvv;
        int t = row0 + j;
        if constexpr (OHM) {
          int s = t >> 2, b2 = t & 3;
          ((unsigned short*)Cp)[((size_t)(b2 * kNh + h) * kSeq + s) * kDk + dd] =
              f2bf(v * scale);
        } else {
          ((float*)Cp)[(size_t)t * N + col] = v;
        }
      }
    }
  }
}

// Block-diagonal flash attention, head-major (B*H, S, dk) in/out.
// Grid 2048: one block per (bh, chunk, half); 4 waves x 32 Q-rows.
// Swapped QK^T: S^T = mfma(K, Q) puts the softmax k-axis lane-local
// (q = lane&15, k = kn*16 + (lane>>4)*4 + j). P then feeds PV directly as
// the A-fragment of v_mfma_f32_16x16x16_bf16 (k granularity 4) - no P LDS.
__global__ __launch_bounds__(256) void attn_blkdiag(const unsigned short* __restrict__ qw,
                                                    const unsigned short* __restrict__ kw,
                                                    const unsigned short* __restrict__ vw,
                                                    unsigned short* __restrict__ ow) {
  __shared__ unsigned short Kl[64 * 64];       // [kv_row][d]   (swizzled)
  __shared__ unsigned short Vt[64 * 64];       // [d][kv_row]   (transposed, swizzled)
  const int tid = (int)threadIdx.x;
  const int w = tid >> 6, l = tid & 63;
  const int l15 = l & 15, l4 = l >> 4;
  const int bid0 = (int)blockIdx.x;
  const int bid = (bid0 & 7) * 256 + (bid0 >> 3);   // XCD swizzle, 2048 % 8 == 0
  const int hf = bid & 1, c = (bid >> 1) & 15, bh = bid >> 5;
  const size_t base = ((size_t)bh * kSeq + c * kChk) * kDk;
  const unsigned short* qp = qw + base + (size_t)hf * 128 * kDk;
  const unsigned short* kp = kw + base;
  const unsigned short* vp = vw + base;

  // Q B-fragments (row = q = m*16+l15, d-slice = kk*32 + l4*8). Scale folded.
  bf16x8 q[2][2];
#pragma unroll
  for (int m = 0; m < 2; ++m)
#pragma unroll
    for (int kk = 0; kk < 2; ++kk)
      q[m][kk] = *(const bf16x8*)(qp + (w * 32 + m * 16 + l15) * 64 + kk * 32 + l4 * 8);

  float mst[2] = {-1e30f, -1e30f}, lst[2] = {0.f, 0.f};
  f32x4 oacc[2][4] = {};

  // Coalesced KV prefetch: each thread owns 32B of the contiguous 8KB tile.
  const int r = tid >> 2, c0 = (tid & 3) * 16;
  u16x8 kr0, kr1, vr0, vr1;
  {
    const unsigned short* kt = kp + tid * 16;
    kr0 = *(const u16x8*)kt; kr1 = *(const u16x8*)(kt + 8);
    const unsigned short* vt = vp + tid * 16;
    vr0 = *(const u16x8*)vt; vr1 = *(const u16x8*)(vt + 8);
  }

  for (int kb = 0; kb < 4; ++kb) {
    __syncthreads();   // previous iteration's K/Vt reads are done
    {
      int bo = r * 128 + c0 * 2;
      *(u16x8*)((char*)Kl + swz(bo)) = kr0;
      *(u16x8*)((char*)Kl + swz(bo + 16)) = kr1;
#pragma unroll
      for (int j = 0; j < 8; ++j) {
        *(unsigned short*)((char*)Vt + swz((c0 + j) * 128 + r * 2)) = vr0[j];
        *(unsigned short*)((char*)Vt + swz((c0 + 8 + j) * 128 + r * 2)) = vr1[j];
      }
    }
    __syncthreads();
    if (kb < 3) {   // T14: issue next-tile loads; latency hides under compute
      const unsigned short* kt = kp + (kb + 1) * (64 * kDk) + tid * 16;
      kr0 = *(const u16x8*)kt; kr1 = *(const u16x8*)(kt + 8);
      const unsigned short* vt = vp + (kb + 1) * (64 * kDk) + tid * 16;
      vr0 = *(const u16x8*)vt; vr1 = *(const u16x8*)(vt + 8);
    }

    // S^T = K Q^T: sacc[kn][m][j] = S[q = m*16+l15][kv = kn*16 + l4*4 + j]
    f32x4 sacc[4][2] = {};
    __builtin_amdgcn_s_setprio(1);
#pragma unroll
    for (int kk = 0; kk < 2; ++kk) {
      bf16x8 kf[4];
#pragma unroll
      for (int kn = 0; kn < 4; ++kn) {
        int bo = (kn * 16 + l15) * 128 + (kk * 32 + l4 * 8) * 2;
        kf[kn] = *(const bf16x8*)((const char*)Kl + swz(bo));
      }
#pragma unroll
      for (int kn = 0; kn < 4; ++kn)
#pragma unroll
        for (int m = 0; m < 2; ++m)
          sacc[kn][m] = __builtin_amdgcn_mfma_f32_16x16x32_bf16(kf[kn], q[m][kk], sacc[kn][m], 0, 0, 0);
    }
    __builtin_amdgcn_s_setprio(0);

    // Lane-local online softmax (exp2 domain) + pack P for PV A-frags.
    unsigned pw[2][4][2];
    float cbq[2][4];
#pragma unroll
    for (int m = 0; m < 2; ++m) {
      float rm = -1e30f;
#pragma unroll
      for (int kn = 0; kn < 4; ++kn)
#pragma unroll
        for (int j = 0; j < 4; ++j) rm = fmaxf(rm, sacc[kn][m][j]);
      rm = fmaxf(rm, __shfl_xor(rm, 16, 64));
      rm = fmaxf(rm, __shfl_xor(rm, 32, 64));
      float mn = fmaxf(mst[m], rm);
      float corr = exp2f(mst[m] - mn);
      mst[m] = mn;
      float rs = 0.f;
#pragma unroll
      for (int kn = 0; kn < 4; ++kn) {
#pragma unroll
        for (int j = 0; j < 4; ++j) {
          float p = exp2f(sacc[kn][m][j] - mn);
          sacc[kn][m][j] = p;
          rs += p;
        }
        pw[m][kn][0] = (unsigned)f2bf(sacc[kn][m][0]) | ((unsigned)f2bf(sacc[kn][m][1]) << 16);
        pw[m][kn][1] = (unsigned)f2bf(sacc[kn][m][2]) | ((unsigned)f2bf(sacc[kn][m][3]) << 16);
      }
      rs += __shfl_xor(rs, 16, 64);
      rs += __shfl_xor(rs, 32, 64);
      lst[m] = lst[m] * corr + rs;
      // corr lives at q=l15; oacc rows are q = l4*4+j -> broadcast.
#pragma unroll
      for (int j = 0; j < 4; ++j) cbq[m][j] = __shfl(corr, l4 * 4 + j, 64);
#pragma unroll
      for (int n = 0; n < 4; ++n)
#pragma unroll
        for (int j = 0; j < 4; ++j) oacc[m][n][j] *= cbq[m][j];
    }

    // O += P @ V via 16x16x16 MFMA: P direct from registers, V^T from LDS (b64).
    __builtin_amdgcn_s_setprio(1);
#pragma unroll
    for (int kn = 0; kn < 4; ++kn) {
      bf16x4 vf[4];
#pragma unroll
      for (int n = 0; n < 4; ++n) {
        int bo = (n * 16 + l15) * 128 + (kn * 16 + l4 * 4) * 2;
        vf[n] = *(const bf16x4*)((const char*)Vt + swz(bo));
      }
#pragma unroll
      for (int m = 0; m < 2; ++m) {
        union { unsigned u[2]; bf16x4 h; } pk;
        pk.u[0] = pw[m][kn][0]; pk.u[1] = pw[m][kn][1];
#pragma unroll
        for (int n = 0; n < 4; ++n)
          oacc[m][n] = mfma16x16(pk.h, vf[n], oacc[m][n]);
      }
    }
    __builtin_amdgcn_s_setprio(0);
  }

  // Normalize + store bf16, head-major. lst lives at q=l15 -> broadcast to rows.
  unsigned short* op = ow + base + (size_t)hf * 128 * kDk;
#pragma unroll
  for (int m = 0; m < 2; ++m) {
    float inv = 1.f / lst[m];
#pragma unroll
    for (int j = 0; j < 4; ++j) {
      float ib = __shfl(inv, l4 * 4 + j, 64);
      int srow = w * 32 + m * 16 + l4 * 4 + j;
#pragma unroll
      for (int n = 0; n < 4; ++n)
        op[(size_t)srow * 64 + n * 16 + l15] = f2bf(oacc[m][n][j] * ib);
    }
  }
}

}  // namespace

extern "C" void kernel_launch(void* const* d_in, const int* in_sizes, int n_in,
                              void* d_out, int out_size, void* d_ws, size_t ws_size,
                              hipStream_t stream) {
  const float* query = (const float*)d_in[0];
  const float* key   = (const float*)d_in[1];
  const float* value = (const float*)d_in[2];
  const float* Wq = (const float*)d_in[3];
  const float* bq = (const float*)d_in[4];
  const float* Wk = (const float*)d_in[5];
  const float* bk = (const float*)d_in[6];
  const float* Wv = (const float*)d_in[7];
  const float* bv = (const float*)d_in[8];
  const float* Wo = (const float*)d_in[9];
  const float* bo = (const float*)d_in[10];

  const float sQ = 0.125f * kLog2e;   // 1/sqrt(dk) * log2(e), folded into Q proj

  const size_t wsz = (size_t)kDm * kDm;          // 1M elems
  const size_t tsz = (size_t)kMr * kDm;          // 16M elems
  unsigned short* wsp = (unsigned short*)d_ws;
  unsigned short* wqb = wsp;                     // Wq|Wk|Wv|Wo contiguous
  unsigned short* wob = wqb + 3 * wsz;
  unsigned short* qws = wqb + 4 * wsz;
  unsigned short* kws = qws + tsz;
  unsigned short* vws = kws + tsz;
  unsigned short* x0  = vws + tsz;               // path A: qbf|kbf|vbf; path B: aws

  const size_t needA = (4 * wsz + 6 * tsz) * 2;  // 200 MB
  const size_t needB = (4 * wsz + 4 * tsz) * 2;  // 136 MB
  if (ws_size < needB) return;

  cvt4<<<dim3(4096), dim3(256), 0, stream>>>(Wq, Wk, Wv, Wo, wqb);

  if (ws_size >= needA) {
    unsigned short* qbf = x0;
    unsigned short* kbf = qbf + tsz;
    unsigned short* vbf = kbf + tsz;
    unsigned short* aws = qbf;                   // reuse after QKV GEMM consumes qbf
    cvt3<<<dim3(49152), dim3(256), 0, stream>>>(query, key, value, qbf);
    gemm_qkv<<<dim3(3072), 256, 0, stream>>>(qbf, kbf, vbf, wqb, bq, bk, bv, qws, sQ);
    attn_blkdiag<<<dim3(2048), 256, 0, stream>>>(qws, kws, vws, aws);
    gemm_bt<2, 0><<<dim3(1024), 256, 0, stream>>>(aws, wob, bo, d_out, 1.0f);
  } else {
    unsigned short* aws = x0;
    gemm_bt<1, 1><<<dim3(1024), 256, 0, stream>>>(query, wqb, bq, qws, sQ);
    gemm_bt<1, 1><<<dim3(1024), 256, 0, stream>>>(key,   wqb + wsz, bk, kws, 1.0f);
    gemm_bt<1, 1><<<dim3(1024), 256, 0, stream>>>(value, wqb + 2 * wsz, bv, vws, 1.0f);
    attn_blkdiag<<<dim3(2048), 256, 0, stream>>>(qws, kws, vws, aws);
    gemm_bt<2, 0><<<dim3(1024), 256, 0, stream>>>(aws, wob, bo, d_out, 1.0f);
  }
}

// Round 6
// 313.857 us; speedup vs baseline: 1.0520x; 1.0520x over previous
//
#include <hip/hip_runtime.h>
#include <hip/hip_bf16.h>

// MemoryEfficientMultiheadAttention: chunked (block-diagonal) MHA.
// S=4096, B=4, D=1024, H=16, dk=64, CHUNK=256.
// cvt(weights, qkv->bf16) -> fused QKV GEMM (3-slot ring, counted vmcnt,
// LDS-staged head-major epilogue) -> flash attn (swapped QK^T, P-in-reg PV)
// -> out proj (3-slot ring).

namespace {

constexpr int kSeq = 4096, kB = 4, kDm = 1024, kNh = 16, kDk = 64, kChk = 256;
constexpr int kMr = kSeq * kB;       // 16384 GEMM rows
constexpr float kLog2e = 1.44269504088896340736f;

typedef __attribute__((ext_vector_type(8))) short bf16x8;
typedef __attribute__((ext_vector_type(4))) short bf16x4;
typedef __attribute__((ext_vector_type(4))) float f32x4;
typedef __attribute__((ext_vector_type(8))) unsigned short u16x8;
typedef __attribute__((ext_vector_type(4))) unsigned short u16x4;

__device__ __forceinline__ unsigned short f2bf(float x) {
  union { float f; unsigned u; } v; v.f = x;
  unsigned r = v.u + 0x7fffu + ((v.u >> 16) & 1u);   // RNE
  return (unsigned short)(r >> 16);
}
// HW packed f32->bf16 (RNE), 1 VALU op for 2 elements.
__device__ __forceinline__ unsigned cvtpk(float lo, float hi) {
  unsigned r;
  asm("v_cvt_pk_bf16_f32 %0, %1, %2" : "=v"(r) : "v"(lo), "v"(hi));
  return r;
}
// XOR swizzle for 128B-row-stride LDS tiles: xor byte bits 4-6 with row&7.
__device__ __forceinline__ int swz(int bo) { return bo ^ ((bo >> 3) & 0x70); }

__device__ __forceinline__ f32x4 mfma16x16(bf16x4 a, bf16x4 b, f32x4 c) {
#if __has_builtin(__builtin_amdgcn_mfma_f32_16x16x16bf16_1k)
  return __builtin_amdgcn_mfma_f32_16x16x16bf16_1k(a, b, c, 0, 0, 0);
#else
  asm volatile("v_mfma_f32_16x16x16_bf16 %0, %1, %2, %0\n\ts_nop 4"
               : "+v"(c) : "v"(a), "v"(b));
  return c;
#endif
}

// All four 1024x1024 weights -> bf16, dst contiguous (Wq|Wk|Wv|Wo).
__global__ __launch_bounds__(256) void cvt4(const float* __restrict__ s0,
                                            const float* __restrict__ s1,
                                            const float* __restrict__ s2,
                                            const float* __restrict__ s3,
                                            unsigned short* __restrict__ dst) {
  int i = blockIdx.x * 256 + threadIdx.x;          // 0 .. 4*2^18-1
  int t = i >> 18;
  int j = i & 0x3ffff;
  const float* s = (t == 0) ? s0 : (t == 1) ? s1 : (t == 2) ? s2 : s3;
  f32x4 v = *(const f32x4*)(s + (size_t)j * 4);
  u16x4 o;
  o[0] = f2bf(v[0]); o[1] = f2bf(v[1]); o[2] = f2bf(v[2]); o[3] = f2bf(v[3]);
  *(u16x4*)(dst + (size_t)i * 4) = o;
}

// query|key|value fp32 -> bf16, three contiguous 16M-elem tensors.
__global__ __launch_bounds__(256) void cvt3(const float* __restrict__ s0,
                                            const float* __restrict__ s1,
                                            const float* __restrict__ s2,
                                            unsigned short* __restrict__ dst) {
  size_t i = (size_t)blockIdx.x * 256 + threadIdx.x;   // 3 * 2^22 chunks
  int t = (int)(i >> 22);
  size_t j = i & 0x3fffff;
  const float* s = (t == 0) ? s0 : (t == 1) ? s1 : s2;
  f32x4 v = *(const f32x4*)(s + j * 4);
  u16x4 o;
  o[0] = f2bf(v[0]); o[1] = f2bf(v[1]); o[2] = f2bf(v[2]); o[3] = f2bf(v[3]);
  *(u16x4*)(dst + i * 4) = o;
}

// Fused QKV projection: C_mat = A_mat @ W_mat^T + b_mat, mat in {q,k,v}.
// 128x128 tile, BK=32, 4 waves. 3-slot LDS ring with counted vmcnt(4):
// loads for K-step t+2 issue at step t; the barrier never drains in-flight
// prefetch. rbi-fastest XCD map keeps the W panel L2-resident.
__global__ __launch_bounds__(256) void gemm_qkv(const unsigned short* __restrict__ qbf,
                                                const unsigned short* __restrict__ kbf,
                                                const unsigned short* __restrict__ vbf,
                                                const unsigned short* __restrict__ Wcat,
                                                const float* __restrict__ bq,
                                                const float* __restrict__ bk,
                                                const float* __restrict__ bv,
                                                unsigned short* __restrict__ dst,
                                                float sQ) {
  constexpr int K = kDm;
  __shared__ unsigned short sh[24576];   // A: slot*4096; B: 12288+slot*4096; epi C: [0,16384)
  const int tid = (int)threadIdx.x;
  const int l = tid & 63;
  const int wbase = tid & ~63;
  const int bid = (int)blockIdx.x;
  // XCD map (3072 % 8 == 0): rbi fastest within XCD -> 16 consecutive blocks
  // share one W panel (256KB, L2-resident); per-XCD A set = 16 panels = 4MB.
  const int rbi = ((bid & 7) << 4) | ((bid >> 3) & 15);   // 0..127
  const int cbi = bid >> 7;                               // 0..23
  const int rb = rbi * 128;
  const int mat = cbi >> 3, ccol = (cbi & 7) * 128;
  const unsigned short* A = (mat == 0) ? qbf : (mat == 1) ? kbf : vbf;
  const float* bp = (mat == 0) ? bq : (mat == 1) ? bk : bv;
  const float scale = (mat == 0) ? sQ : 1.0f;
  unsigned short* out = dst + (size_t)mat * kMr * kDm;
  const int wr = ((tid >> 7) & 1) * 64;
  const int wc = ((tid >> 6) & 1) * 64;
  const int l15 = l & 15, l4 = l >> 4;

  f32x4 acc[4][4] = {};

  auto stage = [&](int slot, int kt) {
    const int k0 = kt << 5;
    unsigned short* AsB = sh + slot * 4096;
    unsigned short* BsB = sh + 12288 + slot * 4096;
#pragma unroll
    for (int i = 0; i < 2; ++i) {
      int ch = i * 256 + tid;
      int rr = ch >> 2, cc = ch & 3;
      const unsigned short* g = A + (size_t)(rb + rr) * K + (k0 + cc * 8);
      __builtin_amdgcn_global_load_lds(
          (const __attribute__((address_space(1))) unsigned int*)g,
          (__attribute__((address_space(3))) unsigned int*)&AsB[(i * 256 + wbase) * 8],
          16, 0, 0);
    }
#pragma unroll
    for (int i = 0; i < 2; ++i) {
      int ch = i * 256 + tid;
      int rr = ch >> 2, cc = ch & 3;
      const unsigned short* g = Wcat + (size_t)(cbi * 128 + rr) * K + (k0 + cc * 8);
      __builtin_amdgcn_global_load_lds(
          (const __attribute__((address_space(1))) unsigned int*)g,
          (__attribute__((address_space(3))) unsigned int*)&BsB[(i * 256 + wbase) * 8],
          16, 0, 0);
    }
  };

  constexpr int nkt = K >> 5;  // 32
  stage(0, 0);
  stage(1, 1);
  asm volatile("s_waitcnt vmcnt(4)" ::: "memory");   // slot0 landed
  __builtin_amdgcn_s_barrier();
  __builtin_amdgcn_sched_barrier(0);

  for (int kt = 0; kt < nkt; ++kt) {
    if (kt + 2 < nkt) stage((kt + 2) % 3, kt + 2);
    const unsigned short* AsC = sh + (kt % 3) * 4096;
    const unsigned short* BsC = sh + 12288 + (kt % 3) * 4096;
    bf16x8 af[4], bfr[4];
#pragma unroll
    for (int m = 0; m < 4; ++m)
      af[m] = *(const bf16x8*)&AsC[(wr + m * 16 + l15) * 32 + l4 * 8];
#pragma unroll
    for (int n = 0; n < 4; ++n)
      bfr[n] = *(const bf16x8*)&BsC[(wc + n * 16 + l15) * 32 + l4 * 8];
#pragma unroll
    for (int m = 0; m < 4; ++m)
#pragma unroll
      for (int n = 0; n < 4; ++n)
        acc[m][n] = __builtin_amdgcn_mfma_f32_16x16x32_bf16(af[m], bfr[n], acc[m][n], 0, 0, 0);
    if (kt + 1 < nkt) {
      if (kt + 2 < nkt) asm volatile("s_waitcnt vmcnt(4)" ::: "memory");  // slot kt+1 landed
      else              asm volatile("s_waitcnt vmcnt(0)" ::: "memory");  // last slot
      __builtin_amdgcn_s_barrier();
      __builtin_amdgcn_sched_barrier(0);
    }
  }

  // All waves done reading the ring before C-restage overwrites it.
  __builtin_amdgcn_s_barrier();
  __builtin_amdgcn_sched_barrier(0);

  // LDS-staged head-major epilogue (coalesced stores; cvt_pk for bf16).
#pragma unroll
  for (int n = 0; n < 4; ++n) {
    int col = wc + n * 16 + l15;                 // tile-local col (< 128)
    float bvv = bp[ccol + col];
    int hh = col >> 6, c64 = col & 63;
#pragma unroll
    for (int m = 0; m < 4; ++m) {
      int sl0 = (wr >> 2) + m * 4 + l4;          // s_local (j-independent)
      unsigned p01 = cvtpk((acc[m][n][0] + bvv) * scale, (acc[m][n][1] + bvv) * scale);
      unsigned p23 = cvtpk((acc[m][n][2] + bvv) * scale, (acc[m][n][3] + bvv) * scale);
      unsigned short e0 = (unsigned short)p01, e1 = (unsigned short)(p01 >> 16);
      unsigned short e2 = (unsigned short)p23, e3 = (unsigned short)(p23 >> 16);
      unsigned short ev[4] = {e0, e1, e2, e3};
#pragma unroll
      for (int j = 0; j < 4; ++j) {
        int or_ = (j * 2 + hh) * 32 + sl0;
        int bo = or_ * 128 + c64 * 2;
        *(unsigned short*)((char*)sh + (bo ^ ((or_ & 7) << 4))) = ev[j];
      }
    }
  }
  __syncthreads();
  {
    int s_local = tid & 31, grp = tid >> 5;      // grp = b2*2 + hh
    int b2 = grp >> 1, hh = grp & 1;
    int h = (ccol >> 6) + hh;
    unsigned short* po =
        out + ((size_t)(b2 * kNh + h) * kSeq + (rb >> 2) + s_local) * kDk;
    const int or_ = tid;
#pragma unroll
    for (int i = 0; i < 8; ++i) {
      int bo = or_ * 128 + i * 16;
      u16x8 vv = *(const u16x8*)((const char*)sh + (bo ^ ((or_ & 7) << 4)));
      *(u16x8*)(po + i * 8) = vv;
    }
  }
}

// Output projection: C[M,N] fp32 = A(head-major bf16) @ Wo^T + bo.
// Same 3-slot ring structure; direct fp32 epilogue (row-major, coalesced-ish).
__global__ __launch_bounds__(256) void gemm_o(const unsigned short* __restrict__ Aw,
                                              const unsigned short* __restrict__ Bw,
                                              const float* __restrict__ bias,
                                              float* __restrict__ Cp) {
  constexpr int K = kDm, N = kDm;
  __shared__ unsigned short sh[24576];
  const int tid = (int)threadIdx.x;
  const int l = tid & 63;
  const int wbase = tid & ~63;
  const int bid = (int)blockIdx.x;
  const int lin = (bid & 7) * 128 + (bid >> 3);   // whole Wo (2MB) L2-fits
  const int rb = (lin >> 3) * 128, cb = (lin & 7) * 128;
  const int wr = ((tid >> 7) & 1) * 64;
  const int wc = ((tid >> 6) & 1) * 64;
  const int l15 = l & 15, l4 = l >> 4;

  f32x4 acc[4][4] = {};

  auto stage = [&](int slot, int kt) {
    const int k0 = kt << 5;
    unsigned short* AsB = sh + slot * 4096;
    unsigned short* BsB = sh + 12288 + slot * 4096;
    int h = k0 >> 6, d0 = k0 & 63;
#pragma unroll
    for (int i = 0; i < 2; ++i) {
      int ch = i * 256 + tid;
      int rr = ch >> 2, cc = ch & 3;
      int t = rb + rr; int s = t >> 2, b2 = t & 3;
      const unsigned short* g =
          Aw + ((size_t)(b2 * kNh + h) * kSeq + s) * kDk + d0 + cc * 8;
      __builtin_amdgcn_global_load_lds(
          (const __attribute__((address_space(1))) unsigned int*)g,
          (__attribute__((address_space(3))) unsigned int*)&AsB[(i * 256 + wbase) * 8],
          16, 0, 0);
    }
#pragma unroll
    for (int i = 0; i < 2; ++i) {
      int ch = i * 256 + tid;
      int rr = ch >> 2, cc = ch & 3;
      const unsigned short* g = Bw + (size_t)(cb + rr) * K + (k0 + cc * 8);
      __builtin_amdgcn_global_load_lds(
          (const __attribute__((address_space(1))) unsigned int*)g,
          (__attribute__((address_space(3))) unsigned int*)&BsB[(i * 256 + wbase) * 8],
          16, 0, 0);
    }
  };

  constexpr int nkt = K >> 5;
  stage(0, 0);
  stage(1, 1);
  asm volatile("s_waitcnt vmcnt(4)" ::: "memory");
  __builtin_amdgcn_s_barrier();
  __builtin_amdgcn_sched_barrier(0);

  for (int kt = 0; kt < nkt; ++kt) {
    if (kt + 2 < nkt) stage((kt + 2) % 3, kt + 2);
    const unsigned short* AsC = sh + (kt % 3) * 4096;
    const unsigned short* BsC = sh + 12288 + (kt % 3) * 4096;
    bf16x8 af[4], bfr[4];
#pragma unroll
    for (int m = 0; m < 4; ++m)
      af[m] = *(const bf16x8*)&AsC[(wr + m * 16 + l15) * 32 + l4 * 8];
#pragma unroll
    for (int n = 0; n < 4; ++n)
      bfr[n] = *(const bf16x8*)&BsC[(wc + n * 16 + l15) * 32 + l4 * 8];
#pragma unroll
    for (int m = 0; m < 4; ++m)
#pragma unroll
      for (int n = 0; n < 4; ++n)
        acc[m][n] = __builtin_amdgcn_mfma_f32_16x16x32_bf16(af[m], bfr[n], acc[m][n], 0, 0, 0);
    if (kt + 1 < nkt) {
      if (kt + 2 < nkt) asm volatile("s_waitcnt vmcnt(4)" ::: "memory");
      else              asm volatile("s_waitcnt vmcnt(0)" ::: "memory");
      __builtin_amdgcn_s_barrier();
      __builtin_amdgcn_sched_barrier(0);
    }
  }

#pragma unroll
  for (int n = 0; n < 4; ++n) {
    int col = cb + wc + n * 16 + l15;
    float bvv = bias[col];
#pragma unroll
    for (int m = 0; m < 4; ++m) {
      int row0 = rb + wr + m * 16 + l4 * 4;
#pragma unroll
      for (int j = 0; j < 4; ++j)
        Cp[(size_t)(row0 + j) * N + col] = acc[m][n][j] + bvv;
    }
  }
}

// C = A @ Bw^T + bias (fallback path only, small-ws).
template <int ALAY, int OHM>
__global__ __launch_bounds__(256) void gemm_bt(const void* __restrict__ Ap,
                                               const unsigned short* __restrict__ Bw,
                                               const float* __restrict__ bias,
                                               void* __restrict__ Cp, float scale) {
  constexpr int K = kDm, N = kDm;
  __shared__ unsigned short As[2][128 * 32];
  __shared__ unsigned short Bs[2][128 * 32];
  const int tid = (int)threadIdx.x;
  const int l = tid & 63;
  const int wbase = tid & ~63;
  const int bid = (int)blockIdx.x;
  const int lin = (bid & 7) * 128 + (bid >> 3);
  const int rb = (lin >> 3) * 128, cb = (lin & 7) * 128;
  const int wr = ((tid >> 7) & 1) * 64;
  const int wc = ((tid >> 6) & 1) * 64;
  const int l15 = l & 15, l4 = l >> 4;

  f32x4 acc[4][4] = {};

  auto stage = [&](int buf, int k0) {
    if constexpr (ALAY == 1) {
      const float* A = (const float*)Ap;
#pragma unroll
      for (int i = 0; i < 4; ++i) {
        int ci = tid + 256 * i;
        int rr = ci >> 3, c4 = ci & 7;
        f32x4 v = *(const f32x4*)(A + (size_t)(rb + rr) * K + (k0 + c4 * 4));
        u16x4 o;
        o[0] = f2bf(v[0]); o[1] = f2bf(v[1]); o[2] = f2bf(v[2]); o[3] = f2bf(v[3]);
        *(u16x4*)&As[buf][rr * 32 + c4 * 4] = o;
      }
    } else {
      const unsigned short* A = (const unsigned short*)Ap;
      int h = k0 >> 6, d0 = k0 & 63;
#pragma unroll
      for (int i = 0; i < 2; ++i) {
        int ch = i * 256 + tid;
        int rr = ch >> 2, cc = ch & 3;
        int t = rb + rr; int s = t >> 2, b2 = t & 3;
        const unsigned short* g =
            A + ((size_t)(b2 * kNh + h) * kSeq + s) * kDk + d0 + cc * 8;
        __builtin_amdgcn_global_load_lds(
            (const __attribute__((address_space(1))) unsigned int*)g,
            (__attribute__((address_space(3))) unsigned int*)&As[buf][(i * 256 + wbase) * 8],
            16, 0, 0);
      }
    }
#pragma unroll
    for (int i = 0; i < 2; ++i) {
      int ch = i * 256 + tid;
      int rr = ch >> 2, cc = ch & 3;
      const unsigned short* g = Bw + (size_t)(cb + rr) * K + (k0 + cc * 8);
      __builtin_amdgcn_global_load_lds(
          (const __attribute__((address_space(1))) unsigned int*)g,
          (__attribute__((address_space(3))) unsigned int*)&Bs[buf][(i * 256 + wbase) * 8],
          16, 0, 0);
    }
  };

  stage(0, 0);
  __syncthreads();
  int cur = 0;
  constexpr int nkt = K >> 5;
  for (int kt = 0; kt < nkt; ++kt) {
    if (kt + 1 < nkt) stage(cur ^ 1, (kt + 1) << 5);
    bf16x8 af[4], bfr[4];
#pragma unroll
    for (int m = 0; m < 4; ++m)
      af[m] = *(const bf16x8*)&As[cur][(wr + m * 16 + l15) * 32 + l4 * 8];
#pragma unroll
    for (int n = 0; n < 4; ++n)
      bfr[n] = *(const bf16x8*)&Bs[cur][(wc + n * 16 + l15) * 32 + l4 * 8];
#pragma unroll
    for (int m = 0; m < 4; ++m)
#pragma unroll
      for (int n = 0; n < 4; ++n)
        acc[m][n] = __builtin_amdgcn_mfma_f32_16x16x32_bf16(af[m], bfr[n], acc[m][n], 0, 0, 0);
    __syncthreads();
    cur ^= 1;
  }

#pragma unroll
  for (int n = 0; n < 4; ++n) {
    int col = cb + wc + n * 16 + l15;
    float bvv = bias[col];
    int h = col >> 6, dd = col & 63;
#pragma unroll
    for (int m = 0; m < 4; ++m) {
      int row0 = rb + wr + m * 16 + l4 * 4;
#pragma unroll
      for (int j = 0; j < 4; ++j) {
        float v = acc[m][n][j] + bvv;
        int t = row0 + j;
        if constexpr (OHM) {
          int s = t >> 2, b2 = t & 3;
          ((unsigned short*)Cp)[((size_t)(b2 * kNh + h) * kSeq + s) * kDk + dd] =
              f2bf(v * scale);
        } else {
          ((float*)Cp)[(size_t)t * N + col] = v;
        }
      }
    }
  }
}

// Block-diagonal flash attention, head-major (B*H, S, dk) in/out.
// Grid 2048: one block per (bh, chunk, half); 4 waves x 32 Q-rows.
// Swapped QK^T: softmax k-axis lane-local; P feeds PV directly from registers.
__global__ __launch_bounds__(256) void attn_blkdiag(const unsigned short* __restrict__ qw,
                                                    const unsigned short* __restrict__ kw,
                                                    const unsigned short* __restrict__ vw,
                                                    unsigned short* __restrict__ ow) {
  __shared__ unsigned short Kl[64 * 64];       // [kv_row][d]   (swizzled)
  __shared__ unsigned short Vt[64 * 64];       // [d][kv_row]   (transposed, swizzled)
  const int tid = (int)threadIdx.x;
  const int w = tid >> 6, l = tid & 63;
  const int l15 = l & 15, l4 = l >> 4;
  const int bid0 = (int)blockIdx.x;
  const int bid = (bid0 & 7) * 256 + (bid0 >> 3);   // XCD swizzle, 2048 % 8 == 0
  const int hf = bid & 1, c = (bid >> 1) & 15, bh = bid >> 5;
  const size_t base = ((size_t)bh * kSeq + c * kChk) * kDk;
  const unsigned short* qp = qw + base + (size_t)hf * 128 * kDk;
  const unsigned short* kp = kw + base;
  const unsigned short* vp = vw + base;

  // Q B-fragments (row = q = m*16+l15, d-slice = kk*32 + l4*8). Scale folded.
  bf16x8 q[2][2];
#pragma unroll
  for (int m = 0; m < 2; ++m)
#pragma unroll
    for (int kk = 0; kk < 2; ++kk)
      q[m][kk] = *(const bf16x8*)(qp + (w * 32 + m * 16 + l15) * 64 + kk * 32 + l4 * 8);

  float mst[2] = {-1e30f, -1e30f}, lst[2] = {0.f, 0.f};
  f32x4 oacc[2][4] = {};

  // Coalesced KV prefetch: each thread owns 32B of the contiguous 8KB tile.
  const int r = tid >> 2, c0 = (tid & 3) * 16;
  u16x8 kr0, kr1, vr0, vr1;
  {
    const unsigned short* kt = kp + tid * 16;
    kr0 = *(const u16x8*)kt; kr1 = *(const u16x8*)(kt + 8);
    const unsigned short* vt = vp + tid * 16;
    vr0 = *(const u16x8*)vt; vr1 = *(const u16x8*)(vt + 8);
  }

  for (int kb = 0; kb < 4; ++kb) {
    __syncthreads();   // previous iteration's K/Vt reads are done
    {
      int bo = r * 128 + c0 * 2;
      *(u16x8*)((char*)Kl + swz(bo)) = kr0;
      *(u16x8*)((char*)Kl + swz(bo + 16)) = kr1;
#pragma unroll
      for (int j = 0; j < 8; ++j) {
        *(unsigned short*)((char*)Vt + swz((c0 + j) * 128 + r * 2)) = vr0[j];
        *(unsigned short*)((char*)Vt + swz((c0 + 8 + j) * 128 + r * 2)) = vr1[j];
      }
    }
    __syncthreads();
    if (kb < 3) {   // T14: issue next-tile loads; latency hides under compute
      const unsigned short* kt = kp + (kb + 1) * (64 * kDk) + tid * 16;
      kr0 = *(const u16x8*)kt; kr1 = *(const u16x8*)(kt + 8);
      const unsigned short* vt = vp + (kb + 1) * (64 * kDk) + tid * 16;
      vr0 = *(const u16x8*)vt; vr1 = *(const u16x8*)(vt + 8);
    }

    // S^T = K Q^T: sacc[kn][m][j] = S[q = m*16+l15][kv = kn*16 + l4*4 + j]
    f32x4 sacc[4][2] = {};
    __builtin_amdgcn_s_setprio(1);
#pragma unroll
    for (int kk = 0; kk < 2; ++kk) {
      bf16x8 kf[4];
#pragma unroll
      for (int kn = 0; kn < 4; ++kn) {
        int bo = (kn * 16 + l15) * 128 + (kk * 32 + l4 * 8) * 2;
        kf[kn] = *(const bf16x8*)((const char*)Kl + swz(bo));
      }
#pragma unroll
      for (int kn = 0; kn < 4; ++kn)
#pragma unroll
        for (int m = 0; m < 2; ++m)
          sacc[kn][m] = __builtin_amdgcn_mfma_f32_16x16x32_bf16(kf[kn], q[m][kk], sacc[kn][m], 0, 0, 0);
    }
    __builtin_amdgcn_s_setprio(0);

    // Lane-local online softmax (exp2 domain) + pack P via v_cvt_pk_bf16_f32.
    unsigned pw[2][4][2];
    float cbq[2][4];
#pragma unroll
    for (int m = 0; m < 2; ++m) {
      float rm = -1e30f;
#pragma unroll
      for (int kn = 0; kn < 4; ++kn)
#pragma unroll
        for (int j = 0; j < 4; ++j) rm = fmaxf(rm, sacc[kn][m][j]);
      rm = fmaxf(rm, __shfl_xor(rm, 16, 64));
      rm = fmaxf(rm, __shfl_xor(rm, 32, 64));
      float mn = fmaxf(mst[m], rm);
      float corr = exp2f(mst[m] - mn);
      mst[m] = mn;
      float rs = 0.f;
#pragma unroll
      for (int kn = 0; kn < 4; ++kn) {
#pragma unroll
        for (int j = 0; j < 4; ++j) {
          float p = exp2f(sacc[kn][m][j] - mn);
          sacc[kn][m][j] = p;
          rs += p;
        }
        pw[m][kn][0] = cvtpk(sacc[kn][m][0], sacc[kn][m][1]);
        pw[m][kn][1] = cvtpk(sacc[kn][m][2], sacc[kn][m][3]);
      }
      rs += __shfl_xor(rs, 16, 64);
      rs += __shfl_xor(rs, 32, 64);
      lst[m] = lst[m] * corr + rs;
      // corr lives at q=l15; oacc rows are q = l4*4+j -> broadcast.
#pragma unroll
      for (int j = 0; j < 4; ++j) cbq[m][j] = __shfl(corr, l4 * 4 + j, 64);
#pragma unroll
      for (int n = 0; n < 4; ++n)
#pragma unroll
        for (int j = 0; j < 4; ++j) oacc[m][n][j] *= cbq[m][j];
    }

    // O += P @ V via 16x16x16 MFMA: P direct from registers, V^T from LDS (b64).
    __builtin_amdgcn_s_setprio(1);
#pragma unroll
    for (int kn = 0; kn < 4; ++kn) {
      bf16x4 vf[4];
#pragma unroll
      for (int n = 0; n < 4; ++n) {
        int bo = (n * 16 + l15) * 128 + (kn * 16 + l4 * 4) * 2;
        vf[n] = *(const bf16x4*)((const char*)Vt + swz(bo));
      }
#pragma unroll
      for (int m = 0; m < 2; ++m) {
        union { unsigned u[2]; bf16x4 h; } pk;
        pk.u[0] = pw[m][kn][0]; pk.u[1] = pw[m][kn][1];
#pragma unroll
        for (int n = 0; n < 4; ++n)
          oacc[m][n] = mfma16x16(pk.h, vf[n], oacc[m][n]);
      }
    }
    __builtin_amdgcn_s_setprio(0);
  }

  // Normalize + store bf16, head-major. lst lives at q=l15 -> broadcast to rows.
  unsigned short* op = ow + base + (size_t)hf * 128 * kDk;
#pragma unroll
  for (int m = 0; m < 2; ++m) {
    float inv = 1.f / lst[m];
#pragma unroll
    for (int j = 0; j < 4; ++j) {
      float ib = __shfl(inv, l4 * 4 + j, 64);
      int srow = w * 32 + m * 16 + l4 * 4 + j;
#pragma unroll
      for (int n = 0; n < 4; ++n)
        op[(size_t)srow * 64 + n * 16 + l15] = f2bf(oacc[m][n][j] * ib);
    }
  }
}

}  // namespace

extern "C" void kernel_launch(void* const* d_in, const int* in_sizes, int n_in,
                              void* d_out, int out_size, void* d_ws, size_t ws_size,
                              hipStream_t stream) {
  const float* query = (const float*)d_in[0];
  const float* key   = (const float*)d_in[1];
  const float* value = (const float*)d_in[2];
  const float* Wq = (const float*)d_in[3];
  const float* bq = (const float*)d_in[4];
  const float* Wk = (const float*)d_in[5];
  const float* bk = (const float*)d_in[6];
  const float* Wv = (const float*)d_in[7];
  const float* bv = (const float*)d_in[8];
  const float* Wo = (const float*)d_in[9];
  const float* bo = (const float*)d_in[10];

  const float sQ = 0.125f * kLog2e;   // 1/sqrt(dk) * log2(e), folded into Q proj

  const size_t wsz = (size_t)kDm * kDm;          // 1M elems
  const size_t tsz = (size_t)kMr * kDm;          // 16M elems
  unsigned short* wsp = (unsigned short*)d_ws;
  unsigned short* wqb = wsp;                     // Wq|Wk|Wv|Wo contiguous
  unsigned short* wob = wqb + 3 * wsz;
  unsigned short* qws = wqb + 4 * wsz;
  unsigned short* kws = qws + tsz;
  unsigned short* vws = kws + tsz;
  unsigned short* x0  = vws + tsz;               // path A: qbf|kbf|vbf; path B: aws

  const size_t needA = (4 * wsz + 6 * tsz) * 2;  // 200 MB
  const size_t needB = (4 * wsz + 4 * tsz) * 2;  // 136 MB
  if (ws_size < needB) return;

  cvt4<<<dim3(4096), dim3(256), 0, stream>>>(Wq, Wk, Wv, Wo, wqb);

  if (ws_size >= needA) {
    unsigned short* qbf = x0;
    unsigned short* kbf = qbf + tsz;
    unsigned short* vbf = kbf + tsz;
    unsigned short* aws = qbf;                   // reuse after QKV GEMM consumes qbf
    cvt3<<<dim3(49152), dim3(256), 0, stream>>>(query, key, value, qbf);
    gemm_qkv<<<dim3(3072), 256, 0, stream>>>(qbf, kbf, vbf, wqb, bq, bk, bv, qws, sQ);
    attn_blkdiag<<<dim3(2048), 256, 0, stream>>>(qws, kws, vws, aws);
    gemm_o<<<dim3(1024), 256, 0, stream>>>(aws, wob, bo, (float*)d_out);
  } else {
    unsigned short* aws = x0;
    gemm_bt<1, 1><<<dim3(1024), 256, 0, stream>>>(query, wqb, bq, qws, sQ);
    gemm_bt<1, 1><<<dim3(1024), 256, 0, stream>>>(key,   wqb + wsz, bk, kws, 1.0f);
    gemm_bt<1, 1><<<dim3(1024), 256, 0, stream>>>(value, wqb + 2 * wsz, bv, vws, 1.0f);
    attn_blkdiag<<<dim3(2048), 256, 0, stream>>>(qws, kws, vws, aws);
    gemm_bt<2, 0><<<dim3(1024), 256, 0, stream>>>(aws, wob, bo, d_out, 1.0f);
  }
}